// Round 4
// baseline (137.802 us; speedup 1.0000x reference)
//
#include <hip/hip_runtime.h>
#include <hip/hip_bf16.h>

typedef __attribute__((ext_vector_type(8))) short bf16x8;
typedef __attribute__((ext_vector_type(4))) float f32x4;

#define N_TOT 8192
#define B_IN  4096
#define D_K   256

typedef __attribute__((address_space(3))) unsigned int lds_uint;
typedef __attribute__((address_space(1))) const unsigned int glob_uint;

__device__ __forceinline__ unsigned short f2bf(float x) {
  unsigned u = __float_as_uint(x);
  u = (u + 0x7FFFu + ((u >> 16) & 1u)) >> 16;
  return (unsigned short)u;
}

__global__ void zero_kernel(int* __restrict__ cnt) {
  int i = blockIdx.x * 256 + threadIdx.x;
  if (i < 1024) cnt[i] = 0;
}

// Normalize each (b,v) row, write bf16 X in anchor order (n = v*B + b), fill labN, histogram cnt.
__global__ void norm_kernel(const float* __restrict__ feat,
                            const int* __restrict__ labels,
                            unsigned short* __restrict__ X,
                            int* __restrict__ labN,
                            int* __restrict__ cnt) {
  int n = blockIdx.x * 4 + (threadIdx.x >> 6);
  int l = threadIdx.x & 63;
  int b = n & (B_IN - 1);
  int v = n >> 12;
  const float4 f = *reinterpret_cast<const float4*>(feat + (size_t)(b * 2 + v) * D_K + l * 4);
  float s = f.x * f.x + f.y * f.y + f.z * f.z + f.w * f.w;
#pragma unroll
  for (int m = 1; m < 64; m <<= 1) s += __shfl_xor(s, m);
  float scale = 1.0f / fmaxf(sqrtf(s), 1e-12f);
  ushort4 o;
  o.x = f2bf(f.x * scale);
  o.y = f2bf(f.y * scale);
  o.z = f2bf(f.z * scale);
  o.w = f2bf(f.w * scale);
  *reinterpret_cast<ushort4*>(X + (size_t)n * D_K + l * 4) = o;
  if (l == 0) {
    int lb = labels[b];
    labN[n] = lb;
    if (n < B_IN) atomicAdd(&cnt[lb], 1);  // integer atomic: deterministic
  }
}

// Main: 512 blocks (32 row-panels x 16 col-splits), 256 threads = 4 waves, 2 blocks/CU.
// Wave w owns rows [rbase + w*64, +64): A resident in 128 VGPRs (K=256).
// Stream 512 cols in 8 tiles of 64 via global_load_lds into 2x32KB LDS double-buffer.
// Source is pre-swizzled (element e -> slot e^(row&7)); reads apply the same XOR.
__global__ __launch_bounds__(256, 2) void main_kernel(const unsigned short* __restrict__ X,
                                                      const int* __restrict__ labN,
                                                      float* __restrict__ SpA,
                                                      float* __restrict__ PpA) {
  __shared__ __align__(16) char Bs[2][32768];
  const int tid = threadIdx.x;
  const int l = tid & 63, w = tid >> 6;
  const int lm = l & 15, lh = l >> 4;
  const int panel = blockIdx.x >> 4;  // 32 panels of 256 rows
  const int split = blockIdx.x & 15;  // 16 splits of 512 cols
  const int rbase = panel * 256;
  const int cbase = split * 512;
  const int wrow = rbase + w * 64;

  // issue async stage of jt=0 into Bs[0]
  {
    char* buf = &Bs[0][0];
#pragma unroll
    for (int i = 0; i < 8; ++i) {
      int c = i * 256 + tid;  // linear LDS int4 slot 0..2047
      int row = c >> 5;
      int c16s = (c & 31) ^ (row & 7);  // inverse-swizzled source slot
      const int4* g = reinterpret_cast<const int4*>(X + (size_t)(cbase + row) * D_K) + c16s;
      char* s = buf + (size_t)(i * 256 + (w << 6)) * 16;  // wave-uniform base (+ lane*16 by HW)
      __builtin_amdgcn_global_load_lds((glob_uint*)g, (lds_uint*)s, 16, 0, 0);
    }
  }

  // A fragments in registers: rows wrow + fi*16 + lm, k = kk*32 + lh*8 .. +7
  bf16x8 a[4][8];
#pragma unroll
  for (int fi = 0; fi < 4; ++fi)
#pragma unroll
    for (int kk = 0; kk < 8; ++kk)
      a[fi][kk] = *reinterpret_cast<const bf16x8*>(
          X + (size_t)(wrow + fi * 16 + lm) * D_K + kk * 32 + lh * 8);

  int labR[4][4];
#pragma unroll
  for (int fi = 0; fi < 4; ++fi)
#pragma unroll
    for (int r = 0; r < 4; ++r) labR[fi][r] = labN[wrow + fi * 16 + lh * 4 + r];

  float S[4][4] = {};
  float Pv[4][4] = {};

  __syncthreads();  // drains jt=0 stage (vmcnt 0 before barrier)

  for (int jt = 0; jt < 8; ++jt) {
    // issue async stage of jt+1 into the other buffer (its last readers passed prev barrier)
    if (jt < 7) {
      char* buf = &Bs[(jt + 1) & 1][0];
      const int col0 = cbase + (jt + 1) * 64;
#pragma unroll
      for (int i = 0; i < 8; ++i) {
        int c = i * 256 + tid;
        int row = c >> 5;
        int c16s = (c & 31) ^ (row & 7);
        const int4* g = reinterpret_cast<const int4*>(X + (size_t)(col0 + row) * D_K) + c16s;
        char* s = buf + (size_t)(i * 256 + (w << 6)) * 16;
        __builtin_amdgcn_global_load_lds((glob_uint*)g, (lds_uint*)s, 16, 0, 0);
      }
    }

    const char* bufc = &Bs[jt & 1][0];
#pragma unroll
    for (int sub = 0; sub < 2; ++sub) {
      f32x4 acc[4][2];
#pragma unroll
      for (int fi = 0; fi < 4; ++fi) {
        acc[fi][0] = (f32x4){0.f, 0.f, 0.f, 0.f};
        acc[fi][1] = (f32x4){0.f, 0.f, 0.f, 0.f};
      }
      const int lrow0 = sub * 32 + lm;
      const int lrow1 = lrow0 + 16;
      const int ba0 = lrow0 * 512, sw0 = (lrow0 & 7) << 4;
      const int ba1 = lrow1 * 512, sw1 = (lrow1 & 7) << 4;
#pragma unroll
      for (int kk = 0; kk < 8; ++kk) {
        int ko = kk * 64 + lh * 16;
        bf16x8 b0 = *reinterpret_cast<const bf16x8*>(bufc + ba0 + (ko ^ sw0));
        bf16x8 b1 = *reinterpret_cast<const bf16x8*>(bufc + ba1 + (ko ^ sw1));
#pragma unroll
        for (int fi = 0; fi < 4; ++fi) {
          acc[fi][0] = __builtin_amdgcn_mfma_f32_16x16x32_bf16(a[fi][kk], b0, acc[fi][0], 0, 0, 0);
          acc[fi][1] = __builtin_amdgcn_mfma_f32_16x16x32_bf16(a[fi][kk], b1, acc[fi][1], 0, 0, 0);
        }
      }
      // epilogue: S += exp(2*dot-2) over ALL cols; Pv += dot over same-label cols (incl self).
      // Self terms removed analytically in the reduce.
      const int cg0 = cbase + jt * 64 + sub * 32 + lm;
      const int labC0 = labN[cg0];
      const int labC1 = labN[cg0 + 16];
#pragma unroll
      for (int fi = 0; fi < 4; ++fi)
#pragma unroll
        for (int fj = 0; fj < 2; ++fj) {
          const int labC = (fj == 0) ? labC0 : labC1;
#pragma unroll
          for (int r = 0; r < 4; ++r) {
            float v = acc[fi][fj][r];
            S[fi][r] += __expf(fmaf(v, 2.0f, -2.0f));
            Pv[fi][r] += (labR[fi][r] == labC) ? v : 0.f;
          }
        }
    }
    __syncthreads();  // drains stage of jt+1, releases buffers
  }

  // reduce S,Pv across the 16 lanes sharing lh; one writer per row per split-slot
#pragma unroll
  for (int fi = 0; fi < 4; ++fi)
#pragma unroll
    for (int r = 0; r < 4; ++r) {
      float s = S[fi][r], p = Pv[fi][r];
#pragma unroll
      for (int m = 1; m < 16; m <<= 1) {
        s += __shfl_xor(s, m);
        p += __shfl_xor(p, m);
      }
      if (lm == 0) {
        int row = wrow + fi * 16 + lh * 4 + r;
        SpA[split * N_TOT + row] = s;
        PpA[split * N_TOT + row] = p;
      }
    }
}

__global__ void reduce1_kernel(const float* __restrict__ Sp, const float* __restrict__ Pp,
                               const int* __restrict__ labN, const int* __restrict__ cnt,
                               float* __restrict__ partial) {
  __shared__ float red[4];
  int tid = threadIdx.x;
  int n = blockIdx.x * 256 + tid;  // 32 blocks x 256 = 8192
  float S = 0.f, Pv = 0.f;
#pragma unroll
  for (int s = 0; s < 16; ++s) {
    S += Sp[s * N_TOT + n];
    Pv += Pp[s * N_TOT + n];
  }
  S -= 1.0f;                      // remove self exp term (exp(2*selfdot-2) ~= 1)
  float P = 2.0f * Pv - 2.0f;     // remove self logit term (~= 2)
  float np = (float)(2 * cnt[labN[n]] - 1);
  float acc = logf(S) + 2.0f - P / np;
#pragma unroll
  for (int m = 1; m < 64; m <<= 1) acc += __shfl_xor(acc, m);
  if ((tid & 63) == 0) red[tid >> 6] = acc;
  __syncthreads();
  if (tid == 0) partial[blockIdx.x] = red[0] + red[1] + red[2] + red[3];
}

__global__ void reduce2_kernel(const float* __restrict__ partial, float* __restrict__ out) {
  int tid = threadIdx.x;  // 64
  float v = (tid < 32) ? partial[tid] : 0.f;
#pragma unroll
  for (int m = 1; m < 64; m <<= 1) v += __shfl_xor(v, m);
  if (tid == 0) out[0] = v * (1.0f / (float)N_TOT);
}

extern "C" void kernel_launch(void* const* d_in, const int* in_sizes, int n_in,
                              void* d_out, int out_size, void* d_ws, size_t ws_size,
                              hipStream_t stream) {
  const float* feat = (const float*)d_in[0];
  const int* labels = (const int*)d_in[1];
  char* ws = (char*)d_ws;
  unsigned short* X = (unsigned short*)ws;       // 8192*256*2 = 4 MB
  int* labN = (int*)(ws + 4194304);              // 32 KB
  int* cnt = (int*)(ws + 4227072);               // 4 KB
  float* Sp = (float*)(ws + 4231168);            // 16*8192*4 = 512 KB
  float* Pp = (float*)(ws + 4755456);            // 512 KB
  float* partial = (float*)(ws + 5279744);       // 128 B
  float* out = (float*)d_out;

  zero_kernel<<<4, 256, 0, stream>>>(cnt);
  norm_kernel<<<2048, 256, 0, stream>>>(feat, labels, X, labN, cnt);
  main_kernel<<<512, 256, 0, stream>>>(X, labN, Sp, Pp);
  reduce1_kernel<<<32, 256, 0, stream>>>(Sp, Pp, labN, cnt, partial);
  reduce2_kernel<<<1, 64, 0, stream>>>(partial, out);
}

// Round 5
// 73.544 us; speedup vs baseline: 1.8737x; 1.8737x over previous
//
#include <hip/hip_runtime.h>
#include <hip/hip_bf16.h>

typedef __attribute__((ext_vector_type(8))) short bf16x8;
typedef __attribute__((ext_vector_type(4))) float f32x4;

#define N_TOT 8192
#define B_IN  4096
#define D_K   256

typedef __attribute__((address_space(3))) unsigned int lds_uint;
typedef __attribute__((address_space(1))) const unsigned int glob_uint;

__device__ __forceinline__ unsigned short f2bf(float x) {
  unsigned u = __float_as_uint(x);
  u = (u + 0x7FFFu + ((u >> 16) & 1u)) >> 16;
  return (unsigned short)u;
}

__global__ void zero_kernel(int* __restrict__ cnt) {
  int i = blockIdx.x * 256 + threadIdx.x;
  if (i < 1024) cnt[i] = 0;
}

// Normalize each (b,v) row, write bf16 X in anchor order (n = v*B + b), fill labN, histogram cnt.
__global__ void norm_kernel(const float* __restrict__ feat,
                            const int* __restrict__ labels,
                            unsigned short* __restrict__ X,
                            int* __restrict__ labN,
                            int* __restrict__ cnt) {
  int n = blockIdx.x * 4 + (threadIdx.x >> 6);
  int l = threadIdx.x & 63;
  int b = n & (B_IN - 1);
  int v = n >> 12;
  const float4 f = *reinterpret_cast<const float4*>(feat + (size_t)(b * 2 + v) * D_K + l * 4);
  float s = f.x * f.x + f.y * f.y + f.z * f.z + f.w * f.w;
#pragma unroll
  for (int m = 1; m < 64; m <<= 1) s += __shfl_xor(s, m);
  float scale = 1.0f / fmaxf(sqrtf(s), 1e-12f);
  ushort4 o;
  o.x = f2bf(f.x * scale);
  o.y = f2bf(f.y * scale);
  o.z = f2bf(f.z * scale);
  o.w = f2bf(f.w * scale);
  *reinterpret_cast<ushort4*>(X + (size_t)n * D_K + l * 4) = o;
  if (l == 0) {
    int lb = labels[b];
    labN[n] = lb;
    if (n < B_IN) atomicAdd(&cnt[lb], 1);  // integer atomic: deterministic
  }
}

// Main: 512 blocks (32 row-panels x 16 col-splits), 256 threads = 4 waves.
// Wave w owns rows [rbase + w*64, +64): A resident in 128 VGPRs (K=256).
// Stream 512 cols in 8 tiles of 64 via global_load_lds into 2x32KB LDS double-buffer.
// Source is pre-swizzled (element e -> slot e^(row&7)); reads apply the same XOR.
// launch_bounds(256,1): 1 wave/EU floor -> full 512-reg unified budget, no spill.
__global__ __launch_bounds__(256, 1) void main_kernel(const unsigned short* __restrict__ X,
                                                      const int* __restrict__ labN,
                                                      float* __restrict__ SpA,
                                                      float* __restrict__ PpA) {
  __shared__ __align__(16) char Bs[2][32768];
  const int tid = threadIdx.x;
  const int l = tid & 63, w = tid >> 6;
  const int lm = l & 15, lh = l >> 4;
  const int panel = blockIdx.x >> 4;  // 32 panels of 256 rows
  const int split = blockIdx.x & 15;  // 16 splits of 512 cols
  const int rbase = panel * 256;
  const int cbase = split * 512;
  const int wrow = rbase + w * 64;

  // issue async stage of jt=0 into Bs[0]
  {
    char* buf = &Bs[0][0];
#pragma unroll
    for (int i = 0; i < 8; ++i) {
      int c = i * 256 + tid;  // linear LDS int4 slot 0..2047
      int row = c >> 5;
      int c16s = (c & 31) ^ (row & 7);  // inverse-swizzled source slot
      const int4* g = reinterpret_cast<const int4*>(X + (size_t)(cbase + row) * D_K) + c16s;
      char* s = buf + (size_t)(i * 256 + (w << 6)) * 16;  // wave-uniform base (+ lane*16 by HW)
      __builtin_amdgcn_global_load_lds((glob_uint*)g, (lds_uint*)s, 16, 0, 0);
    }
  }

  // A fragments in registers: rows wrow + fi*16 + lm, k = kk*32 + lh*8 .. +7
  bf16x8 a[4][8];
#pragma unroll
  for (int fi = 0; fi < 4; ++fi)
#pragma unroll
    for (int kk = 0; kk < 8; ++kk)
      a[fi][kk] = *reinterpret_cast<const bf16x8*>(
          X + (size_t)(wrow + fi * 16 + lm) * D_K + kk * 32 + lh * 8);

  int labR[4][4];
#pragma unroll
  for (int fi = 0; fi < 4; ++fi)
#pragma unroll
    for (int r = 0; r < 4; ++r) labR[fi][r] = labN[wrow + fi * 16 + lh * 4 + r];

  float S[4][4] = {};
  float Pv[4][4] = {};

  __syncthreads();  // drains jt=0 stage (vmcnt 0 before barrier)

  for (int jt = 0; jt < 8; ++jt) {
    // issue async stage of jt+1 into the other buffer (its last readers passed prev barrier)
    if (jt < 7) {
      char* buf = &Bs[(jt + 1) & 1][0];
      const int col0 = cbase + (jt + 1) * 64;
#pragma unroll
      for (int i = 0; i < 8; ++i) {
        int c = i * 256 + tid;
        int row = c >> 5;
        int c16s = (c & 31) ^ (row & 7);
        const int4* g = reinterpret_cast<const int4*>(X + (size_t)(col0 + row) * D_K) + c16s;
        char* s = buf + (size_t)(i * 256 + (w << 6)) * 16;
        __builtin_amdgcn_global_load_lds((glob_uint*)g, (lds_uint*)s, 16, 0, 0);
      }
    }

    const char* bufc = &Bs[jt & 1][0];
#pragma unroll
    for (int sub = 0; sub < 2; ++sub) {
      f32x4 acc[4][2];
#pragma unroll
      for (int fi = 0; fi < 4; ++fi) {
        acc[fi][0] = (f32x4){0.f, 0.f, 0.f, 0.f};
        acc[fi][1] = (f32x4){0.f, 0.f, 0.f, 0.f};
      }
      const int lrow0 = sub * 32 + lm;
      const int lrow1 = lrow0 + 16;
      const int ba0 = lrow0 * 512, sw0 = (lrow0 & 7) << 4;
      const int ba1 = lrow1 * 512, sw1 = (lrow1 & 7) << 4;
#pragma unroll
      for (int kk = 0; kk < 8; ++kk) {
        int ko = kk * 64 + lh * 16;
        bf16x8 b0 = *reinterpret_cast<const bf16x8*>(bufc + ba0 + (ko ^ sw0));
        bf16x8 b1 = *reinterpret_cast<const bf16x8*>(bufc + ba1 + (ko ^ sw1));
#pragma unroll
        for (int fi = 0; fi < 4; ++fi) {
          acc[fi][0] = __builtin_amdgcn_mfma_f32_16x16x32_bf16(a[fi][kk], b0, acc[fi][0], 0, 0, 0);
          acc[fi][1] = __builtin_amdgcn_mfma_f32_16x16x32_bf16(a[fi][kk], b1, acc[fi][1], 0, 0, 0);
        }
      }
      // epilogue: S += exp(2*dot-2) over ALL cols; Pv += dot over same-label cols (incl self).
      // Self terms removed analytically in the reduce.
      const int cg0 = cbase + jt * 64 + sub * 32 + lm;
      const int labC0 = labN[cg0];
      const int labC1 = labN[cg0 + 16];
#pragma unroll
      for (int fi = 0; fi < 4; ++fi)
#pragma unroll
        for (int fj = 0; fj < 2; ++fj) {
          const int labC = (fj == 0) ? labC0 : labC1;
#pragma unroll
          for (int r = 0; r < 4; ++r) {
            float v = acc[fi][fj][r];
            S[fi][r] += __expf(fmaf(v, 2.0f, -2.0f));
            Pv[fi][r] += (labR[fi][r] == labC) ? v : 0.f;
          }
        }
    }
    __syncthreads();  // drains stage of jt+1, releases buffers
  }

  // reduce S,Pv across the 16 lanes sharing lh; one writer per row per split-slot
#pragma unroll
  for (int fi = 0; fi < 4; ++fi)
#pragma unroll
    for (int r = 0; r < 4; ++r) {
      float s = S[fi][r], p = Pv[fi][r];
#pragma unroll
      for (int m = 1; m < 16; m <<= 1) {
        s += __shfl_xor(s, m);
        p += __shfl_xor(p, m);
      }
      if (lm == 0) {
        int row = wrow + fi * 16 + lh * 4 + r;
        SpA[split * N_TOT + row] = s;
        PpA[split * N_TOT + row] = p;
      }
    }
}

__global__ void reduce1_kernel(const float* __restrict__ Sp, const float* __restrict__ Pp,
                               const int* __restrict__ labN, const int* __restrict__ cnt,
                               float* __restrict__ partial) {
  __shared__ float red[4];
  int tid = threadIdx.x;
  int n = blockIdx.x * 256 + tid;  // 32 blocks x 256 = 8192
  float S = 0.f, Pv = 0.f;
#pragma unroll
  for (int s = 0; s < 16; ++s) {
    S += Sp[s * N_TOT + n];
    Pv += Pp[s * N_TOT + n];
  }
  S -= 1.0f;                      // remove self exp term (exp(2*selfdot-2) ~= 1)
  float P = 2.0f * Pv - 2.0f;     // remove self logit term (~= 2)
  float np = (float)(2 * cnt[labN[n]] - 1);
  float acc = logf(S) + 2.0f - P / np;
#pragma unroll
  for (int m = 1; m < 64; m <<= 1) acc += __shfl_xor(acc, m);
  if ((tid & 63) == 0) red[tid >> 6] = acc;
  __syncthreads();
  if (tid == 0) partial[blockIdx.x] = red[0] + red[1] + red[2] + red[3];
}

__global__ void reduce2_kernel(const float* __restrict__ partial, float* __restrict__ out) {
  int tid = threadIdx.x;  // 64
  float v = (tid < 32) ? partial[tid] : 0.f;
#pragma unroll
  for (int m = 1; m < 64; m <<= 1) v += __shfl_xor(v, m);
  if (tid == 0) out[0] = v * (1.0f / (float)N_TOT);
}

extern "C" void kernel_launch(void* const* d_in, const int* in_sizes, int n_in,
                              void* d_out, int out_size, void* d_ws, size_t ws_size,
                              hipStream_t stream) {
  const float* feat = (const float*)d_in[0];
  const int* labels = (const int*)d_in[1];
  char* ws = (char*)d_ws;
  unsigned short* X = (unsigned short*)ws;       // 8192*256*2 = 4 MB
  int* labN = (int*)(ws + 4194304);              // 32 KB
  int* cnt = (int*)(ws + 4227072);               // 4 KB
  float* Sp = (float*)(ws + 4231168);            // 16*8192*4 = 512 KB
  float* Pp = (float*)(ws + 4755456);            // 512 KB
  float* partial = (float*)(ws + 5279744);       // 128 B
  float* out = (float*)d_out;

  zero_kernel<<<4, 256, 0, stream>>>(cnt);
  norm_kernel<<<2048, 256, 0, stream>>>(feat, labels, X, labN, cnt);
  main_kernel<<<512, 256, 0, stream>>>(X, labN, Sp, Pp);
  reduce1_kernel<<<32, 256, 0, stream>>>(Sp, Pp, labN, cnt, partial);
  reduce2_kernel<<<1, 64, 0, stream>>>(partial, out);
}